// Round 10
// baseline (186.973 us; speedup 1.0000x reference)
//
#include <hip/hip_runtime.h>
#include <math.h>

// Problem constants (match reference)
#define B_    4
#define T_    2048
#define D_    1024
#define F_    4096
#define R_    (B_*T_)      // 8192 rows (b,t)
#define SEG_  64           // segments per time-chain
#define L_    (T_/SEG_)    // 32 steps per segment
#define DECAYF 0.9f
#define OMDF   0.1f        // 1 - decay
// Flag threshold below 0.5: the k4 fallback re-tests at exactly 0.5 in fp32,
// so flags only need NO FALSE NEGATIVES. fp8(x8-scaled) GEMM error is
// ~1e-3 RMS (6-sigma ~7e-3); margin 0.05 is ~7x worst plausible error.
#define FLAG_THRESH 0.45f

typedef __attribute__((ext_vector_type(4)))  int   i32x4;
typedef __attribute__((ext_vector_type(8)))  int   i32x8;
typedef __attribute__((ext_vector_type(16))) float f32x16;

// MFMA operand fragment: two dwordx4 loads land directly in the halves of
// the 8-reg tuple (R10: the R9 element-wise (i32x8){...} assembly cost ~80
// extra VGPRs + v_movs; VGPR_Count 224 pinned occupancy at 2 blocks/CU).
union fragu { i32x8 v; i32x4 h[2]; };

// pack 4 floats into 4 fp8 e4m3 bytes (byte0 = first arg)
__device__ __forceinline__ int pk_fp8x4(float x, float y, float z, float w) {
    int p = 0;
    p = __builtin_amdgcn_cvt_pk_fp8_f32(x, y, p, false);  // bytes 0,1
    p = __builtin_amdgcn_cvt_pk_fp8_f32(z, w, p, true);   // bytes 2,3
    return p;
}

// ---------------------------------------------------------------------------
// PACKED OPERAND LAYOUT (R9): k2 needs NO LDS:
//   panel P = row>>5 (32 rows), k-chunk C = kbyte>>6 (64 B) -> 2 KB tile at
//   byte ((P*16 + C) * 2048). Within a tile, byte  h*1024 + l*16 + t  holds
//   element [row = P*32 + (l&31)][k = C*64 + (l>>5)*32 + h*16 + t].
// A wave's 32x32x64 fragment load = two 1 KB contiguous global_load_dwordx4
// (lane l at l*16, halves at +0/+1024) — perfectly coalesced, straight to
// VGPRs, zero LDS, zero barriers.
__device__ __forceinline__ size_t pk_off(int row, int d) {
    // byte offset of element [row][d] in the packed layout
    return ((size_t)((row >> 5) * 16 + (d >> 6)) * 2048)
         + ((d >> 4) & 1) * 1024
         + ((row & 31) + ((d >> 5) & 1) * 32) * 16
         + (d & 15);
}

// ---------------------------------------------------------------------------
// KA: fused prologue. Grid-partitioned roles:
//   blocks [0, 4096):       W1 fp32 -> fp8 e4m3 x8, packed operand layout
//   blocks [4096, 4352):    per-segment EMA end-state (seg_sum)
//   blocks [4352, 4384):    zero the 8192 per-row spike flags
#define KA_W1_BLOCKS  4096
#define KA_SEG_BLOCKS 256
#define KA_FLAG_BLOCKS 32

__global__ __launch_bounds__(256)
void kA_prologue(const float* __restrict__ spikes,
                 const float* __restrict__ W1,
                 unsigned char* __restrict__ w_f8,
                 float* __restrict__ seg_sum,
                 unsigned int* __restrict__ flags) {
    const int bid = blockIdx.x;
    const int tid = threadIdx.x;
    if (bid < KA_W1_BLOCKS) {
        int i = bid * 256 + tid;                  // float4 index over W1 [F x D]
        float4 v = ((const float4*)W1)[i];
        int f  = i >> 8;                          // D/4 = 256 groups per row
        int d0 = (i & 255) * 4;
        *(int*)(w_f8 + pk_off(f, d0)) = pk_fp8x4(8.f*v.x, 8.f*v.y, 8.f*v.z, 8.f*v.w);
    } else if (bid < KA_W1_BLOCKS + KA_SEG_BLOCKS) {
        int t = (bid - KA_W1_BLOCKS) * 256 + tid; // B_*SEG_*D_/4 threads
        int dg = t & (D_ / 4 - 1);
        int s = (t >> 8) & (SEG_ - 1);
        int b = t >> 14;
        const float4* sp4 = (const float4*)spikes;
        const int base = (b * T_ + s * L_) * (D_ / 4) + dg;
        float4 e = {0.f, 0.f, 0.f, 0.f};
#pragma unroll 8
        for (int k = 0; k < L_; ++k) {
            float4 x = sp4[base + k * (D_ / 4)];
            e.x = DECAYF * e.x + OMDF * x.x;
            e.y = DECAYF * e.y + OMDF * x.y;
            e.z = DECAYF * e.z + OMDF * x.z;
            e.w = DECAYF * e.w + OMDF * x.w;
        }
        ((float4*)seg_sum)[(b * SEG_ + s) * (D_ / 4) + dg] = e;
    } else {
        int i = (bid - KA_W1_BLOCKS - KA_SEG_BLOCKS) * 256 + tid;
        if (i < R_) flags[i] = 0u;
    }
}

// ---------------------------------------------------------------------------
// KB: weighted Kogge-Stone scan over the 64 segments of each (b,d) chain,
// one chain per 64-lane wave (lane = segment). start_state[s] = scan[s-1].
__global__ __launch_bounds__(256)
void kB_seg_scan(const float* __restrict__ seg_sum,
                 float* __restrict__ start_state) {
    int g = blockIdx.x * 256 + threadIdx.x;   // B_*D_*64 threads
    int s = g & 63;                           // segment = lane
    int c = g >> 6;                           // chain id: 0..B_*D_-1
    int d = c & (D_ - 1);
    int b = c >> 10;
    int idx = (b * SEG_ + s) * D_ + d;
    float v = seg_sum[idx];
    float wp = 0.0343368382f;                 // 0.9^32 (per-segment decay)
#pragma unroll
    for (int off = 1; off < SEG_; off <<= 1) {
        float u = __shfl_up(v, off, 64);
        if (s >= off) v += wp * u;
        wp *= wp;                             // w^1, w^2, w^4, ...
    }
    float pv = __shfl_up(v, 1, 64);
    start_state[idx] = (s == 0) ? 0.f : pv;
}

// ---------------------------------------------------------------------------
// KC: recompute segment-local EMA seeded with start_state; emit fp8 (x8)
// into the packed operand layout. For thread (b,s,dg): global row
// r = b*T + s*32 + k, so P = b*64+s and r&31 = k — the tile indices are
// loop-invariant; successive k just steps the in-tile lane slot by 16 B.
__global__ __launch_bounds__(256)
void kC_ema_fp8(const float* __restrict__ spikes,
                const float* __restrict__ start_state,
                unsigned char* __restrict__ a_f8) {
    int t = blockIdx.x * 256 + threadIdx.x;            // B_*SEG_*D_/4 threads
    int dg = t & (D_ / 4 - 1);
    int s = (t >> 8) & (SEG_ - 1);
    int b = t >> 14;
    const float4* sp4 = (const float4*)spikes;
    const int base = (b * T_ + s * L_) * (D_ / 4) + dg;
    const int d0 = dg * 4;
    unsigned char* dst = a_f8 + pk_off(b * T_ + s * L_, d0);   // k=0 element
    float4 e = ((const float4*)start_state)[(b * SEG_ + s) * (D_ / 4) + dg];
#pragma unroll 8
    for (int k = 0; k < L_; ++k) {
        float4 x = sp4[base + k * (D_ / 4)];
        e.x = DECAYF * e.x + OMDF * x.x;
        e.y = DECAYF * e.y + OMDF * x.y;
        e.z = DECAYF * e.z + OMDF * x.z;
        e.w = DECAYF * e.w + OMDF * x.w;
        *(int*)(dst + k * 16) = pk_fp8x4(8.f*e.x, 8.f*e.y, 8.f*e.z, 8.f*e.w);
    }
}

// ---------------------------------------------------------------------------
// K2: MX-fp8 32x32x64 streaming GEMM, NO LDS, NO BARRIERS (R9 structure).
// R10: fragment halves loaded through union fragu so the two dwordx4 land
// directly in the MFMA operand tuple (no element-wise reassembly). 128x128
// block tile, 4 waves 2x2, each wave a 2x2 grid of 32x32x64 MFMAs; 2-stage
// register prefetch; compiler emits fine-grained vmcnt (no barrier drains).
// Uniform e8m0 scales = 2^-3 (values stored x8) keep acc exact in scale.
// NOTE: plain __launch_bounds__(256). R5's (256,3) floor spilled the
// accumulators to scratch (WRITE_SIZE 557 MB). Never floor-cap this kernel.
__global__ __launch_bounds__(256)
void k2_mfma_flags(const unsigned char* __restrict__ Ap,  // packed a_f8
                   const unsigned char* __restrict__ Bp,  // packed w_f8
                   unsigned int* __restrict__ flags) {
    const int tid = threadIdx.x;
    const int w = tid >> 6;
    const int lane = tid & 63;
    const int m0 = blockIdx.y * 128;
    const int n0 = blockIdx.x * 128;
    const int wm = w >> 1, wn = w & 1;
    const int kg = lane >> 5;

    // Per-lane stream base pointers: 4 operand streams (2 A tiles, 2 B tiles).
    // Panel P's 16 k-tiles are contiguous (32 KB); iter C reads at +C*2048.
    const unsigned char* a0 = Ap + ((size_t)((m0 >> 5) + wm * 2 + 0) * 16) * 2048 + lane * 16;
    const unsigned char* a1 = Ap + ((size_t)((m0 >> 5) + wm * 2 + 1) * 16) * 2048 + lane * 16;
    const unsigned char* b0 = Bp + ((size_t)((n0 >> 5) + wn * 2 + 0) * 16) * 2048 + lane * 16;
    const unsigned char* b1 = Bp + ((size_t)((n0 >> 5) + wn * 2 + 1) * 16) * 2048 + lane * 16;

    f32x16 acc[2][2] = {};

#define LDFRAG(dst, p, C)                                                   \
    {                                                                       \
        (dst).h[0] = *(const i32x4*)((p) + (size_t)(C) * 2048);             \
        (dst).h[1] = *(const i32x4*)((p) + (size_t)(C) * 2048 + 1024);      \
    }

#define MFMA4(AF0, AF1, BF0, BF1)                                           \
    {                                                                       \
        acc[0][0] = __builtin_amdgcn_mfma_scale_f32_32x32x64_f8f6f4(        \
            AF0.v, BF0.v, acc[0][0], 0, 0, 0, 124, 0, 124);                 \
        acc[0][1] = __builtin_amdgcn_mfma_scale_f32_32x32x64_f8f6f4(        \
            AF0.v, BF1.v, acc[0][1], 0, 0, 0, 124, 0, 124);                 \
        acc[1][0] = __builtin_amdgcn_mfma_scale_f32_32x32x64_f8f6f4(        \
            AF1.v, BF0.v, acc[1][0], 0, 0, 0, 124, 0, 124);                 \
        acc[1][1] = __builtin_amdgcn_mfma_scale_f32_32x32x64_f8f6f4(        \
            AF1.v, BF1.v, acc[1][1], 0, 0, 0, 124, 0, 124);                 \
    }

    // 2-stage register prefetch over 16 k-chunks, unrolled x2 (two frag
    // sets, no register copies). Final prefetch wraps to C=0 (harmless).
    fragu A0a, A1a, B0a, B1a, A0b, A1b, B0b, B1b;
    LDFRAG(A0a, a0, 0); LDFRAG(A1a, a1, 0);
    LDFRAG(B0a, b0, 0); LDFRAG(B1a, b1, 0);
#pragma unroll
    for (int C = 0; C < 16; C += 2) {
        LDFRAG(A0b, a0, C + 1); LDFRAG(A1b, a1, C + 1);
        LDFRAG(B0b, b0, C + 1); LDFRAG(B1b, b1, C + 1);
        MFMA4(A0a, A1a, B0a, B1a);
        const int C2 = (C + 2) & 15;
        LDFRAG(A0a, a0, C2); LDFRAG(A1a, a1, C2);
        LDFRAG(B0a, b0, C2); LDFRAG(B1a, b1, C2);
        MFMA4(A0b, A1b, B0b, B1b);
    }
#undef LDFRAG
#undef MFMA4

    // Epilogue: per-row spike flags. 32x32 C/D layout (m74/m101-verified):
    // col = lane&31, row = (reg&3) + 8*(reg>>2) + 4*(lane>>5).
#pragma unroll
    for (int i = 0; i < 2; ++i) {
#pragma unroll
        for (int reg = 0; reg < 16; ++reg) {
            float mx = fmaxf(acc[i][0][reg], acc[i][1][reg]);
            if (mx > FLAG_THRESH) {
                const int rr = (reg & 3) + 8 * (reg >> 2) + 4 * kg;
                atomicOr(&flags[m0 + wm * 64 + i * 32 + rr], 1u);
            }
        }
    }
}

// ---------------------------------------------------------------------------
// K4: one block per (b,t) row. Unflagged rows (the overwhelmingly common
// case) write zeros. Flagged rows take the exact fp32 slow path, rebuilding
// the EMA row from start_state + <=32 spike rows.
__global__ __launch_bounds__(256)
void k4_output(const float* __restrict__ spikes,
               const float* __restrict__ start_state,
               const float* __restrict__ W1,
               const float* __restrict__ Wr,
               const float* __restrict__ W2,
               const unsigned int* __restrict__ flags,
               float* __restrict__ out) {
    const int row = blockIdx.x;          // 0..R_-1
    const int tid = threadIdx.x;
    float4 o = {0.f, 0.f, 0.f, 0.f};

    if (flags[row] == 0u) {              // wave-uniform branch (per block)
        *(float4*)&out[(size_t)row * D_ + tid * 4] = o;
        return;
    }

    __shared__ float se[D_];
    __shared__ float sp[D_];
    __shared__ float red[256];
    __shared__ int nspk;
    __shared__ int spk_list[256];

    const int b = row / T_;
    const int t = row % T_;
    const int seg = t / L_;
    const int off = t % L_;
    const int segbase = (b * T_ + seg * L_) * D_;

    for (int i = tid; i < D_; i += 256) {
        float e = start_state[(b * SEG_ + seg) * D_ + i];
        for (int j = 0; j <= off; ++j)
            e = DECAYF * e + OMDF * spikes[segbase + j * D_ + i];
        se[i] = e;
        sp[i] = spikes[(size_t)row * D_ + i];
    }
    if (tid == 0) nspk = 0;
    __syncthreads();

    for (int f0 = 0; f0 < F_; f0 += 256) {
        int f = f0 + tid;
        float mix = 0.f;
        for (int k = 0; k < D_; ++k) mix += se[k] * W1[(size_t)f * D_ + k];
        if (mix > 0.5f) {
            int idx = atomicAdd(&nspk, 1);
            spk_list[idx] = f;
        }
        __syncthreads();
        int n = nspk;
        for (int i = 0; i < n; ++i) {
            int fs = spk_list[i];
            float part = 0.f;
#pragma unroll
            for (int k = 0; k < 4; ++k)
                part += sp[tid * 4 + k] * Wr[(size_t)fs * D_ + tid * 4 + k];
            red[tid] = part;
            __syncthreads();
            for (int sft = 128; sft > 0; sft >>= 1) {
                if (tid < sft) red[tid] += red[tid + sft];
                __syncthreads();
            }
            float r = 1.f / (1.f + expf(-red[0]));
            __syncthreads();
            o.x += r * W2[(size_t)(tid * 4 + 0) * F_ + fs];
            o.y += r * W2[(size_t)(tid * 4 + 1) * F_ + fs];
            o.z += r * W2[(size_t)(tid * 4 + 2) * F_ + fs];
            o.w += r * W2[(size_t)(tid * 4 + 3) * F_ + fs];
        }
        __syncthreads();
        if (tid == 0) nspk = 0;
        __syncthreads();
    }
    *(float4*)&out[(size_t)row * D_ + tid * 4] = o;
}

// ---------------------------------------------------------------------------
extern "C" void kernel_launch(void* const* d_in, const int* in_sizes, int n_in,
                              void* d_out, int out_size, void* d_ws, size_t ws_size,
                              hipStream_t stream) {
    const float* spikes = (const float*)d_in[0];   // [B,T,D]
    const float* W1     = (const float*)d_in[1];   // [F,D]
    const float* W2     = (const float*)d_in[2];   // [D,F]
    const float* Wr     = (const float*)d_in[3];   // [F,D]
    float* out = (float*)d_out;                    // [B,T,D]

    // workspace layout (~14.3 MB total)
    char* ws = (char*)d_ws;
    float* seg_sum      = (float*)ws;                                // 1 MB
    float* start_state  = seg_sum + (size_t)B_ * SEG_ * D_;          // 1 MB
    unsigned int* flags = (unsigned int*)(start_state + (size_t)B_ * SEG_ * D_); // 32 KB
    unsigned char* a_f8 = (unsigned char*)(flags + R_);              // 8 MB, packed
    unsigned char* w_f8 = a_f8 + (size_t)R_ * D_;                    // 4 MB, packed

    kA_prologue<<<KA_W1_BLOCKS + KA_SEG_BLOCKS + KA_FLAG_BLOCKS, 256, 0, stream>>>(
        spikes, W1, w_f8, seg_sum, flags);
    kB_seg_scan<<<(B_ * D_ * 64) / 256, 256, 0, stream>>>(seg_sum, start_state);
    kC_ema_fp8<<<(B_ * SEG_ * D_ / 4) / 256, 256, 0, stream>>>(spikes, start_state, a_f8);

    dim3 g2(F_ / 128, R_ / 128);
    k2_mfma_flags<<<g2, 256, 0, stream>>>(a_f8, w_f8, flags);

    k4_output<<<R_, 256, 0, stream>>>(spikes, start_state, W1, Wr, W2, flags, out);
}